// Round 19
// baseline (57.715 us; speedup 1.0000x reference)
//
#include <hip/hip_runtime.h>
#include <math.h>

#define N_ATOMS  50000
#define N_NBRS   32
#define N_GAUSS  25
#define RCUT     5.0f
#define TT       192       // nearest-table nodes, spacing RCUT/191
#define TROWS    32
#define NTB      6         // 192/32 table-build blocks
#define MAXZ     100
#define NT64     782       // ceil(50000/64) 64-atom chunks
#define PBLOCKS  256       // persistent fused blocks (1 per CU)
#define NPAIR    (N_ATOMS * N_NBRS)        // 1,600,000
#define PKPAD    (NT64 * 2048)             // 1,601,536 (padded)
#define PKB      782                       // pk-precompute blocks (2048 pairs each)
#define PI_F     3.14159265358979323846f

typedef unsigned int   uint_t;
typedef unsigned short ushort_t;
typedef _Float16 f16;
typedef f16   f16x2 __attribute__((ext_vector_type(2)));
typedef f16   f16x4 __attribute__((ext_vector_type(4)));
typedef f16   f16x8 __attribute__((ext_vector_type(8)));
typedef float f32x4 __attribute__((ext_vector_type(4)));

// fast shifted softplus: max(x,0) + log(0.5 + 0.5*exp(-|x|))
__device__ __forceinline__ float ssp(float x) {
  return fmaxf(x, 0.0f) + __logf(fmaf(0.5f, __expf(-fabsf(x)), 0.5f));
}
__device__ __forceinline__ f16x2 bch(uint_t u) {
  return __builtin_bit_cast(f16x2, u);
}
__device__ __forceinline__ uint_t hcb(f16x2 v) {
  return __builtin_bit_cast(uint_t, v);
}
// swizzled element offset into a [16][128] f16 LDS tile
__device__ __forceinline__ int swz(int m, int e) {
  return m * 128 + ((((e >> 3) ^ m) & 15) << 3) + (e & 7);
}

// ---- prep: [0,NTB) table; [NTB,NTB+64) transposes+ytab; [NTB+64,...) pair codes
__global__ void __launch_bounds__(256, 2)
prep_all_kernel(const float* __restrict__ fw1,
                const float* __restrict__ fb1,
                const float* __restrict__ fw2,
                const float* __restrict__ fb2,
                const float* __restrict__ w1,
                const float* __restrict__ w2,
                const float* __restrict__ mw1,
                const float* __restrict__ embed,
                const float* __restrict__ in2f,
                const float* __restrict__ dR,
                const int* __restrict__ nbr,
                const int* __restrict__ Z,
                f16* __restrict__ tabh,
                f16* __restrict__ ytab,
                f16* __restrict__ w1ht,
                f16* __restrict__ w2ht,
                f16* __restrict__ mw1ht,
                uint_t* __restrict__ pkAll) {
  const int tid = threadIdx.x;
  const int bid = blockIdx.x;

  __shared__ float sW2[128 * 128];       // 64 KB
  __shared__ float sH[TROWS][128];       // 16 KB

  if (bid >= NTB + 64) {
    // ---- pair-code precompute: pk = i0 | (Z[nbr] << 8) ----
    const int base = (bid - NTB - 64) * 2048;
    #pragma unroll
    for (int t0 = 0; t0 < 8; ++t0) {
      const int idx = base + t0 * 256 + tid;
      if (idx < PKPAD) {
        uint_t pk = 0;
        if (idx < NPAIR) {
          const float r = dR[idx];
          const int  nb = nbr[idx];
          int i0 = (int)(r * (191.0f / RCUT) + 0.5f);
          i0 = min(i0, 191);
          pk = (uint_t)i0 | ((uint_t)Z[nb] << 8);
        }
        pkAll[idx] = pk;
      }
    }
    return;
  }

  if (bid < NTB) {
    const int i0 = bid * TROWS;
    #pragma unroll
    for (int t = 0; t < 16; ++t) {
      const int e = tid + t * 256;
      ((float4*)sW2)[e] = ((const float4*)fw2)[e];
    }
    {
      const int f  = tid & 127;
      const int rh = (tid >> 7) * (TROWS / 2);
      const float delta = RCUT / (float)(N_GAUSS - 1);
      const float coeff = -0.5f / (delta * delta);
      const float b1v = fb1[f];
      for (int j = 0; j < TROWS / 2; ++j) {
        const float r = (float)(i0 + rh + j) * (RCUT / 191.0f);
        float h = b1v;
        #pragma unroll
        for (int g = 0; g < N_GAUSS; ++g) {
          const float d = r - (float)g * delta;
          h = fmaf(__expf(coeff * d * d), fw1[g * 128 + f], h);
        }
        sH[rh + j][f] = ssp(h);
      }
    }
    __syncthreads();
    {
      const int c0 = (tid & 31) * 4;
      const int rg = (tid >> 5) * 4;
      f32x4 acc[4];
      const float4 bv = *(const float4*)&fb2[c0];
      #pragma unroll
      for (int j = 0; j < 4; ++j) acc[j] = (f32x4){bv.x, bv.y, bv.z, bv.w};
      for (int k = 0; k < 128; ++k) {
        const float4 wv = *(const float4*)&sW2[k * 128 + c0];
        #pragma unroll
        for (int j = 0; j < 4; ++j) {
          const float hv = sH[rg + j][k];
          acc[j][0] = fmaf(hv, wv.x, acc[j][0]);
          acc[j][1] = fmaf(hv, wv.y, acc[j][1]);
          acc[j][2] = fmaf(hv, wv.z, acc[j][2]);
          acc[j][3] = fmaf(hv, wv.w, acc[j][3]);
        }
      }
      #pragma unroll
      for (int j = 0; j < 4; ++j) {
        const int i = i0 + rg + j;
        const float r = (float)i * (RCUT / 191.0f);
        const float fc = (r < RCUT) ? 0.5f * (__cosf(r * PI_F / RCUT) + 1.0f) : 0.0f;
        f16x4 o;
        #pragma unroll
        for (int c = 0; c < 4; ++c) o[c] = (f16)(acc[j][c] * fc);
        *(f16x4*)&tabh[i * 128 + c0] = o;
      }
    }
  } else {
    const int cc = (bid - NTB) * 2 + (tid >> 7);
    const int i  = tid & 127;
    w1ht[cc * 128 + i] = (f16)w1[i * 128 + cc];
    w2ht[cc * 128 + i] = (f16)w2[i * 128 + cc];
    if (cc < 64) mw1ht[cc * 128 + i] = (f16)mw1[i * 64 + cc];
    float* xs = &sH[0][0] + (tid >> 7) * 128;
    xs[i] = (cc < MAXZ) ? embed[cc * 128 + i] : 0.0f;
    __syncthreads();
    if (cc < MAXZ) {
      float acc = 0.0f;
      for (int j = 0; j < 128; j += 4) {
        const float4 xv = *reinterpret_cast<const float4*>(&xs[j]);
        acc = fmaf(xv.x, in2f[(j + 0) * 128 + i], acc);
        acc = fmaf(xv.y, in2f[(j + 1) * 128 + i], acc);
        acc = fmaf(xv.z, in2f[(j + 2) * 128 + i], acc);
        acc = fmaf(xv.w, in2f[(j + 3) * 128 + i], acc);
      }
      ytab[cc * 128 + i] = (f16)acc;
    }
  }
}

// ---- fused kernel: 64-atom chunks, 3 barriers/chunk, same-wave cross-chunk pipeline.
// cfconv: quarter-wave owns 2 atoms (16 load-groups/chunk, split 5/5/6 over phases).
// dense: each 4-wave group handles 2 tiles per phase.
__global__ void __launch_bounds__(512, 2)
fused_kernel(const uint_t* __restrict__ pkAll,
             const int* __restrict__ Z,
             const float* __restrict__ embed,
             const f16* __restrict__ tabh,
             const f16* __restrict__ ytab,
             const f16* __restrict__ w1ht, const float* __restrict__ b1,
             const f16* __restrict__ w2ht, const float* __restrict__ b2,
             const f16* __restrict__ mw1ht, const float* __restrict__ mb1,
             const float* __restrict__ mw2,
             float* __restrict__ partial) {
  const int tid = threadIdx.x;
  const int w   = tid >> 6;         // wave 0..7
  const int l   = tid & 63;
  const int q   = l >> 4;           // quarter
  const int cq  = l & 15;
  const int bid = blockIdx.x;

  __shared__ __align__(16) f16    sW[TT * 128];      // 48 KB nearest table
  __shared__ __align__(16) f16    sYT[MAXZ * 128];   // 25.6 KB y rows
  __shared__ __align__(16) uint_t s_pk[2][2048];     // 16 KB pair codes (dbuf)
  __shared__ __align__(16) f16    aggB[2][64 * 128]; // 32 KB agg (dbuf)
  __shared__ __align__(16) f16    sB[64 * 128];      // 16 KB h1
  __shared__ __align__(16) f16    sX[64 * 128];      // 16 KB xnew
  __shared__ int   sZb[2][64];
  __shared__ float sRed[8];

  for (int e = tid; e < TT * 16; e += 512)   ((uint4*)sW)[e]  = ((const uint4*)tabh)[e];
  for (int e = tid; e < MAXZ * 16; e += 512) ((uint4*)sYT)[e] = ((const uint4*)ytab)[e];

  // dense role indices
  const int gg  = w >> 2;           // tile-group: handles tiles gg*2, gg*2+1
  const int wvg = w & 3;
  const int rc  = cq;
  const int qk  = q;
  f16x8 bw1[2][4], bw2[2][4], bwm[4];
  float bb1[2], bb2[2];
  #pragma unroll
  for (int t = 0; t < 2; ++t) {
    const int c = wvg * 32 + t * 16 + rc;
    bb1[t] = b1[c];
    bb2[t] = b2[c];
    #pragma unroll
    for (int k0i = 0; k0i < 4; ++k0i) {
      bw1[t][k0i] = *(const f16x8*)&w1ht[c * 128 + k0i * 32 + qk * 8];
      bw2[t][k0i] = *(const f16x8*)&w2ht[c * 128 + k0i * 32 + qk * 8];
    }
  }
  const int c1 = wvg * 16 + rc;
  #pragma unroll
  for (int k0i = 0; k0i < 4; ++k0i)
    bwm[k0i] = *(const f16x8*)&mw1ht[c1 * 128 + k0i * 32 + qk * 8];
  const float bm = mb1[c1];
  const float cm = mw2[c1];

  // cfconv role indices: quarter q owns atoms m0q, m0q+1 within the 64-chunk
  const int m0q = w * 8 + q * 2;
  const char* wb = (const char*)sW  + cq * 16;
  const char* yb = (const char*)sYT + cq * 16;

  const int myChunks = (NT64 - 1 - bid) / PBLOCKS + 1;
  float vsum = 0.0f;

  f16x2 acc[2][4];                  // [atom-in-quarter][channel-word]
  uint4 twA[4], ytA[4], twB[4], ytB[4];

#define STAGE(bb, cc) { \
    const uint4 v = *(const uint4*)&pkAll[(size_t)(cc) * 2048 + tid * 4]; \
    *(uint4*)&s_pk[bb][tid * 4] = v; \
    if (tid < 64) sZb[bb][tid] = ((cc) * 64 + tid < N_ATOMS) ? Z[(cc) * 64 + tid] : 0; }

// group gi in [0,16): slot s = gi*4+d; atom = m0q + (s>>5); k = s&31
#define IG(BK, bb, gi) { \
    _Pragma("unroll") \
    for (int d = 0; d < 4; ++d) { \
      const int s = (gi) * 4 + d; \
      const uint_t pk = s_pk[bb][(m0q + (s >> 5)) * N_NBRS + (s & 31)]; \
      tw##BK[d] = *(const uint4*)(wb + ((pk & 0xFFu) << 8)); \
      yt##BK[d] = *(const uint4*)(yb + ((pk >> 8) << 8)); \
    } }

#define CG(BK, gi) { \
    _Pragma("unroll") \
    for (int d = 0; d < 4; ++d) { \
      const int al = (((gi) * 4 + d) >> 5); \
      acc[al][0] += bch(tw##BK[d].x) * bch(yt##BK[d].x); \
      acc[al][1] += bch(tw##BK[d].y) * bch(yt##BK[d].y); \
      acc[al][2] += bch(tw##BK[d].z) * bch(yt##BK[d].z); \
      acc[al][3] += bch(tw##BK[d].w) * bch(yt##BK[d].w); \
    } }

#define AGGW(bb) { \
    _Pragma("unroll") \
    for (int al = 0; al < 2; ++al) { \
      uint4 o; \
      o.x = hcb(acc[al][0]); o.y = hcb(acc[al][1]); \
      o.z = hcb(acc[al][2]); o.w = hcb(acc[al][3]); \
      const int am = m0q + al; \
      const int mm = am & 15; \
      *(uint4*)&aggB[bb][(am >> 4) * 2048 + mm * 128 + (((cq ^ mm) & 15) << 3)] = o; \
    } }

#define ACCZ { \
    _Pragma("unroll") \
    for (int al = 0; al < 2; ++al) { \
      _Pragma("unroll") \
      for (int c = 0; c < 4; ++c) acc[al][c] = (f16x2)0; \
    } }

#define AFRAGP(P, k0) (*(const f16x8*)&(P)[rc * 128 + (((((k0) >> 3) + qk) ^ rc) & 15) * 8])

  // ---- prologue: stage chunks 0 and 1, full cfconv for chunk 0 ----
  STAGE(0, bid)
  if (1 < myChunks) STAGE(1, bid + PBLOCKS)
  __syncthreads();     // tables + pk visible
  ACCZ
  IG(A, 0, 0) IG(B, 0, 1)
  CG(A, 0) IG(A, 0, 2)
  CG(B, 1) IG(B, 0, 3)
  CG(A, 2) IG(A, 0, 4)
  CG(B, 3) IG(B, 0, 5)
  CG(A, 4) IG(A, 0, 6)
  CG(B, 5) IG(B, 0, 7)
  CG(A, 6) IG(A, 0, 8)
  CG(B, 7) IG(B, 0, 9)
  CG(A, 8) IG(A, 0, 10)
  CG(B, 9) IG(B, 0, 11)
  CG(A, 10) IG(A, 0, 12)
  CG(B, 11) IG(B, 0, 13)
  CG(A, 12) IG(A, 0, 14)
  CG(B, 13) IG(B, 0, 15)
  CG(A, 14)
  CG(B, 15)
  AGGW(0)
  __syncthreads();     // aggB[0] ready

  // ---- main loop: 3 barriers per 64-atom chunk ----
  for (int s = 0; s < myChunks; ++s) {
    const int b  = s & 1;
    const int cc = bid + s * PBLOCKS;
    const bool hn = (s + 1 < myChunks);
    const int nb_ = b ^ 1;

    if (hn) ACCZ

    // Phase 1: dense L1 (2 tiles) || cfconv groups 0-4 of next chunk
    if (hn) { IG(A, nb_, 0) IG(B, nb_, 1) }
    #pragma unroll
    for (int ti = 0; ti < 2; ++ti) {
      const int tt = gg * 2 + ti;
      const f16* aggp = &aggB[b][tt * 2048];
      f16* hB = &sB[tt * 2048];
      f32x4 dacc[2];
      #pragma unroll
      for (int t = 0; t < 2; ++t) dacc[t] = (f32x4){bb1[t], bb1[t], bb1[t], bb1[t]};
      #pragma unroll
      for (int k0i = 0; k0i < 4; ++k0i) {
        const f16x8 af = AFRAGP(aggp, k0i * 32);
        #pragma unroll
        for (int t = 0; t < 2; ++t)
          dacc[t] = __builtin_amdgcn_mfma_f32_16x16x32_f16(af, bw1[t][k0i], dacc[t], 0, 0, 0);
      }
      #pragma unroll
      for (int t = 0; t < 2; ++t) {
        const int c = wvg * 32 + t * 16 + rc;
        #pragma unroll
        for (int r = 0; r < 4; ++r) hB[swz(qk * 4 + r, c)] = (f16)ssp(dacc[t][r]);
      }
    }
    if (hn) {
      CG(A, 0) IG(A, nb_, 2)
      CG(B, 1) IG(B, nb_, 3)
      CG(A, 2) IG(A, nb_, 4)
      CG(B, 3)
      CG(A, 4)
    }
    __syncthreads();   // B1: sB ready

    // Phase 2: dense L2 + residual (2 tiles) || cfconv groups 5-9
    if (hn) { IG(A, nb_, 5) IG(B, nb_, 6) }
    #pragma unroll
    for (int ti = 0; ti < 2; ++ti) {
      const int tt = gg * 2 + ti;
      const f16* hB = &sB[tt * 2048];
      f16* hX = &sX[tt * 2048];
      f32x4 dacc[2];
      #pragma unroll
      for (int t = 0; t < 2; ++t) dacc[t] = (f32x4){bb2[t], bb2[t], bb2[t], bb2[t]};
      #pragma unroll
      for (int k0i = 0; k0i < 4; ++k0i) {
        const f16x8 af = AFRAGP(hB, k0i * 32);
        #pragma unroll
        for (int t = 0; t < 2; ++t)
          dacc[t] = __builtin_amdgcn_mfma_f32_16x16x32_f16(af, bw2[t][k0i], dacc[t], 0, 0, 0);
      }
      #pragma unroll
      for (int t = 0; t < 2; ++t) {
        const int c = wvg * 32 + t * 16 + rc;
        #pragma unroll
        for (int r = 0; r < 4; ++r) {
          const int mm = qk * 4 + r;
          const float x = embed[(size_t)sZb[b][tt * 16 + mm] * 128 + c] + dacc[t][r];
          hX[swz(mm, c)] = (f16)x;
        }
      }
    }
    if (hn) {
      CG(A, 5) IG(A, nb_, 7)
      CG(B, 6) IG(B, nb_, 8)
      CG(A, 7) IG(A, nb_, 9)
      CG(B, 8)
      CG(A, 9)
    }
    __syncthreads();   // B2: sX ready

    // Phase 3: MLP (2 tiles) || cfconv groups 10-15 + agg write || stage s+2
    if (hn) { IG(A, nb_, 10) IG(B, nb_, 11) }
    if (s + 2 < myChunks) STAGE(b, bid + (s + 2) * PBLOCKS)
    #pragma unroll
    for (int ti = 0; ti < 2; ++ti) {
      const int tt = gg * 2 + ti;
      const f16* hX = &sX[tt * 2048];
      f32x4 a2 = (f32x4){bm, bm, bm, bm};
      #pragma unroll
      for (int k0i = 0; k0i < 4; ++k0i)
        a2 = __builtin_amdgcn_mfma_f32_16x16x32_f16(AFRAGP(hX, k0i * 32), bwm[k0i], a2, 0, 0, 0);
      #pragma unroll
      for (int r = 0; r < 4; ++r) {
        const int atom = cc * 64 + tt * 16 + qk * 4 + r;
        if (atom < N_ATOMS) vsum = fmaf(ssp(a2[r]), cm, vsum);
      }
    }
    if (hn) {
      CG(A, 10) IG(A, nb_, 12)
      CG(B, 11) IG(B, nb_, 13)
      CG(A, 12) IG(A, nb_, 14)
      CG(B, 13) IG(B, nb_, 15)
      CG(A, 14)
      CG(B, 15)
      AGGW(nb_)
    }
    __syncthreads();   // B3: aggB[nb_] + s_pk[b] complete; sB/sX free
  }
#undef STAGE
#undef IG
#undef CG
#undef AGGW
#undef ACCZ
#undef AFRAGP

  // ---- block reduce -> partial ----
  #pragma unroll
  for (int o = 1; o < 64; o <<= 1) vsum += __shfl_xor(vsum, o, 64);
  if (l == 0) sRed[w] = vsum;
  __syncthreads();
  if (tid == 0) {
    float sF = 0.0f;
    #pragma unroll
    for (int i = 0; i < 8; ++i) sF += sRed[i];
    partial[bid] = sF;
  }
}

// ---- final reduce: one block sums the partials, applies bias + scale ----
__global__ void __launch_bounds__(256, 1)
reduce_kernel(const float* __restrict__ partial,
              const float* __restrict__ mb2,
              float* __restrict__ out) {
  const int tid = threadIdx.x;
  float s = 0.0f;
  for (int i = tid; i < PBLOCKS; i += 256) s += partial[i];
  __shared__ float sr[4];
  #pragma unroll
  for (int o = 1; o < 64; o <<= 1) s += __shfl_xor(s, o, 64);
  if ((tid & 63) == 0) sr[tid >> 6] = s;
  __syncthreads();
  if (tid == 0) {
    out[0] = 20.0f * (sr[0] + sr[1] + sr[2] + sr[3] + (float)N_ATOMS * mb2[0]);
  }
}

extern "C" void kernel_launch(void* const* d_in, const int* in_sizes, int n_in,
                              void* d_out, int out_size, void* d_ws, size_t ws_size,
                              hipStream_t stream) {
  const float* dR    = (const float*)d_in[0];
  const int*   Z     = (const int*)  d_in[1];
  const int*   nbr   = (const int*)  d_in[2];
  const float* embed = (const float*)d_in[3];
  const float* fw1   = (const float*)d_in[4];
  const float* fb1   = (const float*)d_in[5];
  const float* fw2   = (const float*)d_in[6];
  const float* fb2   = (const float*)d_in[7];
  const float* in2f  = (const float*)d_in[8];
  const float* w1    = (const float*)d_in[9];
  const float* b1    = (const float*)d_in[10];
  const float* w2    = (const float*)d_in[11];
  const float* b2    = (const float*)d_in[12];
  const float* mw1   = (const float*)d_in[13];
  const float* mb1   = (const float*)d_in[14];
  const float* mw2   = (const float*)d_in[15];
  const float* mb2   = (const float*)d_in[16];
  float* out = (float*)d_out;

  char* ws = (char*)d_ws;
  f16*    tabh    = (f16*)ws;                               // 48 KB
  f16*    ytab    = (f16*)(ws + (size_t)64 * 1024);         // 25.6 KB
  f16*    w1ht    = (f16*)(ws + (size_t)128 * 1024);        // 32 KB
  f16*    w2ht    = (f16*)(ws + (size_t)192 * 1024);        // 32 KB
  f16*    mw1ht   = (f16*)(ws + (size_t)256 * 1024);        // 16 KB
  float*  partial = (float*)(ws + (size_t)384 * 1024);      // 1 KB
  uint_t* pkAll   = (uint_t*)(ws + (size_t)1024 * 1024);    // 6.4 MB

  prep_all_kernel<<<NTB + 64 + PKB, 256, 0, stream>>>(fw1, fb1, fw2, fb2,
      w1, w2, mw1, embed, in2f, dR, nbr, Z,
      tabh, ytab, w1ht, w2ht, mw1ht, pkAll);
  fused_kernel<<<PBLOCKS, 512, 0, stream>>>(pkAll, Z, embed,
      tabh, ytab, w1ht, b1, w2ht, b2, mw1ht, mb1, mw2, partial);
  reduce_kernel<<<1, 256, 0, stream>>>(partial, mb2, out);
}

// Round 20
// 52.419 us; speedup vs baseline: 1.1010x; 1.1010x over previous
//
#include <hip/hip_runtime.h>
#include <math.h>

#define N_ATOMS  50000
#define N_NBRS   32
#define N_GAUSS  25
#define RCUT     5.0f
#define TT       192       // nearest-table nodes, spacing RCUT/191
#define TROWS    32
#define NTB      6         // 192/32 table-build blocks
#define MAXZ     100
#define NT32     1563      // ceil(50000/32) 32-atom chunks
#define PBLOCKS  256       // persistent fused blocks (1 per CU)
#define NPAIR    (N_ATOMS * N_NBRS)        // 1,600,000
#define PKPAD    (NT32 * 1024)             // 1,600,512 (padded)
#define PKB      782                       // pk-precompute blocks (2048 pairs each)
#define PI_F     3.14159265358979323846f

typedef unsigned int   uint_t;
typedef unsigned short ushort_t;
typedef _Float16 f16;
typedef f16   f16x2 __attribute__((ext_vector_type(2)));
typedef f16   f16x4 __attribute__((ext_vector_type(4)));
typedef f16   f16x8 __attribute__((ext_vector_type(8)));
typedef float f32x4 __attribute__((ext_vector_type(4)));

// fast shifted softplus: max(x,0) + log(0.5 + 0.5*exp(-|x|))
__device__ __forceinline__ float ssp(float x) {
  return fmaxf(x, 0.0f) + __logf(fmaf(0.5f, __expf(-fabsf(x)), 0.5f));
}
__device__ __forceinline__ f16x2 bch(uint_t u) {
  return __builtin_bit_cast(f16x2, u);
}
__device__ __forceinline__ uint_t hcb(f16x2 v) {
  return __builtin_bit_cast(uint_t, v);
}
// swizzled element offset into a [16][128] f16 LDS tile
__device__ __forceinline__ int swz(int m, int e) {
  return m * 128 + ((((e >> 3) ^ m) & 15) << 3) + (e & 7);
}

// ---- prep: [0,NTB) table; [NTB,NTB+64) transposes+ytab; [NTB+64,...) pair codes
__global__ void __launch_bounds__(256, 2)
prep_all_kernel(const float* __restrict__ fw1,
                const float* __restrict__ fb1,
                const float* __restrict__ fw2,
                const float* __restrict__ fb2,
                const float* __restrict__ w1,
                const float* __restrict__ w2,
                const float* __restrict__ mw1,
                const float* __restrict__ embed,
                const float* __restrict__ in2f,
                const float* __restrict__ dR,
                const int* __restrict__ nbr,
                const int* __restrict__ Z,
                const float* __restrict__ mb2,
                f16* __restrict__ tabh,
                f16* __restrict__ ytab,
                f16* __restrict__ w1ht,
                f16* __restrict__ w2ht,
                f16* __restrict__ mw1ht,
                uint_t* __restrict__ pkAll,
                float* __restrict__ out) {
  const int tid = threadIdx.x;
  const int bid = blockIdx.x;
  if (bid == 0 && tid == 0) {
    out[0] = 20.0f * (float)N_ATOMS * mb2[0];   // seed with bias term; fused adds the rest
  }

  __shared__ float sW2[128 * 128];       // 64 KB
  __shared__ float sH[TROWS][128];       // 16 KB

  if (bid >= NTB + 64) {
    // ---- pair-code precompute: pk = i0 | (Z[nbr] << 8) ----
    const int base = (bid - NTB - 64) * 2048;
    #pragma unroll
    for (int t0 = 0; t0 < 8; ++t0) {
      const int idx = base + t0 * 256 + tid;
      if (idx < PKPAD) {
        uint_t pk = 0;
        if (idx < NPAIR) {
          const float r = dR[idx];
          const int  nb = nbr[idx];
          int i0 = (int)(r * (191.0f / RCUT) + 0.5f);
          i0 = min(i0, 191);
          pk = (uint_t)i0 | ((uint_t)Z[nb] << 8);
        }
        pkAll[idx] = pk;
      }
    }
    return;
  }

  if (bid < NTB) {
    const int i0 = bid * TROWS;
    #pragma unroll
    for (int t = 0; t < 16; ++t) {
      const int e = tid + t * 256;
      ((float4*)sW2)[e] = ((const float4*)fw2)[e];
    }
    {
      const int f  = tid & 127;
      const int rh = (tid >> 7) * (TROWS / 2);
      const float delta = RCUT / (float)(N_GAUSS - 1);
      const float coeff = -0.5f / (delta * delta);
      const float b1v = fb1[f];
      for (int j = 0; j < TROWS / 2; ++j) {
        const float r = (float)(i0 + rh + j) * (RCUT / 191.0f);
        float h = b1v;
        #pragma unroll
        for (int g = 0; g < N_GAUSS; ++g) {
          const float d = r - (float)g * delta;
          h = fmaf(__expf(coeff * d * d), fw1[g * 128 + f], h);
        }
        sH[rh + j][f] = ssp(h);
      }
    }
    __syncthreads();
    {
      const int c0 = (tid & 31) * 4;
      const int rg = (tid >> 5) * 4;
      f32x4 acc[4];
      const float4 bv = *(const float4*)&fb2[c0];
      #pragma unroll
      for (int j = 0; j < 4; ++j) acc[j] = (f32x4){bv.x, bv.y, bv.z, bv.w};
      for (int k = 0; k < 128; ++k) {
        const float4 wv = *(const float4*)&sW2[k * 128 + c0];
        #pragma unroll
        for (int j = 0; j < 4; ++j) {
          const float hv = sH[rg + j][k];
          acc[j][0] = fmaf(hv, wv.x, acc[j][0]);
          acc[j][1] = fmaf(hv, wv.y, acc[j][1]);
          acc[j][2] = fmaf(hv, wv.z, acc[j][2]);
          acc[j][3] = fmaf(hv, wv.w, acc[j][3]);
        }
      }
      #pragma unroll
      for (int j = 0; j < 4; ++j) {
        const int i = i0 + rg + j;
        const float r = (float)i * (RCUT / 191.0f);
        const float fc = (r < RCUT) ? 0.5f * (__cosf(r * PI_F / RCUT) + 1.0f) : 0.0f;
        f16x4 o;
        #pragma unroll
        for (int c = 0; c < 4; ++c) o[c] = (f16)(acc[j][c] * fc);
        *(f16x4*)&tabh[i * 128 + c0] = o;
      }
    }
  } else {
    const int cc = (bid - NTB) * 2 + (tid >> 7);
    const int i  = tid & 127;
    w1ht[cc * 128 + i] = (f16)w1[i * 128 + cc];
    w2ht[cc * 128 + i] = (f16)w2[i * 128 + cc];
    if (cc < 64) mw1ht[cc * 128 + i] = (f16)mw1[i * 64 + cc];
    float* xs = &sH[0][0] + (tid >> 7) * 128;
    xs[i] = (cc < MAXZ) ? embed[cc * 128 + i] : 0.0f;
    __syncthreads();
    if (cc < MAXZ) {
      float acc = 0.0f;
      for (int j = 0; j < 128; j += 4) {
        const float4 xv = *reinterpret_cast<const float4*>(&xs[j]);
        acc = fmaf(xv.x, in2f[(j + 0) * 128 + i], acc);
        acc = fmaf(xv.y, in2f[(j + 1) * 128 + i], acc);
        acc = fmaf(xv.z, in2f[(j + 2) * 128 + i], acc);
        acc = fmaf(xv.w, in2f[(j + 3) * 128 + i], acc);
      }
      ytab[cc * 128 + i] = (f16)acc;
    }
  }
}

// ---- fused kernel: same-wave cross-chunk pipeline, precomputed pair codes,
//      3 barriers/chunk; finishes with ONE atomicAdd per block (no reduce kernel).
__global__ void __launch_bounds__(512, 2)
fused_kernel(const uint_t* __restrict__ pkAll,
             const int* __restrict__ Z,
             const float* __restrict__ embed,
             const f16* __restrict__ tabh,
             const f16* __restrict__ ytab,
             const f16* __restrict__ w1ht, const float* __restrict__ b1,
             const f16* __restrict__ w2ht, const float* __restrict__ b2,
             const f16* __restrict__ mw1ht, const float* __restrict__ mb1,
             const float* __restrict__ mw2,
             float* __restrict__ out) {
  const int tid = threadIdx.x;
  const int w   = tid >> 6;         // wave 0..7
  const int l   = tid & 63;
  const int q   = l >> 4;           // quarter
  const int cq  = l & 15;
  const int bid = blockIdx.x;

  __shared__ __align__(16) f16    sW[TT * 128];      // 48 KB nearest table
  __shared__ __align__(16) f16    sYT[MAXZ * 128];   // 25.6 KB y rows
  __shared__ __align__(16) uint_t s_pk[2][1024];     // 8 KB pair codes (dbuf)
  __shared__ __align__(16) f16    aggB[2][32 * 128]; // 16 KB agg (dbuf)
  __shared__ __align__(16) f16    sB[32 * 128];      // 8 KB h1
  __shared__ __align__(16) f16    sX[32 * 128];      // 8 KB xnew
  __shared__ int   sZb[2][32];
  __shared__ float sRed[8];

  for (int e = tid; e < TT * 16; e += 512)   ((uint4*)sW)[e]  = ((const uint4*)tabh)[e];
  for (int e = tid; e < MAXZ * 16; e += 512) ((uint4*)sYT)[e] = ((const uint4*)ytab)[e];

  // dense role indices
  const int g   = w >> 2;           // 16-atom tile within chunk
  const int wvg = w & 3;
  const int rc  = cq;
  const int qk  = q;
  f16x8 bw1[2][4], bw2[2][4], bwm[4];
  float bb1[2], bb2[2];
  #pragma unroll
  for (int t = 0; t < 2; ++t) {
    const int c = wvg * 32 + t * 16 + rc;
    bb1[t] = b1[c];
    bb2[t] = b2[c];
    #pragma unroll
    for (int k0i = 0; k0i < 4; ++k0i) {
      bw1[t][k0i] = *(const f16x8*)&w1ht[c * 128 + k0i * 32 + qk * 8];
      bw2[t][k0i] = *(const f16x8*)&w2ht[c * 128 + k0i * 32 + qk * 8];
    }
  }
  const int c1 = wvg * 16 + rc;
  #pragma unroll
  for (int k0i = 0; k0i < 4; ++k0i)
    bwm[k0i] = *(const f16x8*)&mw1ht[c1 * 128 + k0i * 32 + qk * 8];
  const float bm = mb1[c1];
  const float cm = mw2[c1];

  // cfconv role indices
  const int m = w * 4 + q;          // atom within 32-chunk
  const char* wb = (const char*)sW  + cq * 16;
  const char* yb = (const char*)sYT + cq * 16;

  const int myChunks = (NT32 - 1 - bid) / PBLOCKS + 1;
  float vsum = 0.0f;

  f16x2 acc[4];
  uint4 twA[4], ytA[4], twB[4], ytB[4];

#define STAGE(bb, cc) { \
    const uint2 v = *(const uint2*)&pkAll[(cc) * 1024 + tid * 2]; \
    *(uint2*)&s_pk[bb][tid * 2] = v; \
    if (tid < 32) sZb[bb][tid] = ((cc) * 32 + tid < N_ATOMS) ? Z[(cc) * 32 + tid] : 0; }

#define IG(BK, bb, gi) { \
    _Pragma("unroll") \
    for (int d = 0; d < 4; ++d) { \
      const uint_t pk = s_pk[bb][m * N_NBRS + (gi) * 4 + d]; \
      tw##BK[d] = *(const uint4*)(wb + ((pk & 0xFFu) << 8)); \
      yt##BK[d] = *(const uint4*)(yb + ((pk >> 8) << 8)); \
    } }

#define CG(BK) { \
    _Pragma("unroll") \
    for (int d = 0; d < 4; ++d) { \
      acc[0] += bch(tw##BK[d].x) * bch(yt##BK[d].x); \
      acc[1] += bch(tw##BK[d].y) * bch(yt##BK[d].y); \
      acc[2] += bch(tw##BK[d].z) * bch(yt##BK[d].z); \
      acc[3] += bch(tw##BK[d].w) * bch(yt##BK[d].w); \
    } }

#define AGGW(bb) { \
    uint4 o; \
    o.x = hcb(acc[0]); o.y = hcb(acc[1]); o.z = hcb(acc[2]); o.w = hcb(acc[3]); \
    const int mm = m & 15; \
    *(uint4*)&aggB[bb][(m >> 4) * 2048 + mm * 128 + (((cq ^ mm) & 15) << 3)] = o; }

#define AFRAGP(P, k0) (*(const f16x8*)&(P)[rc * 128 + (((((k0) >> 3) + qk) ^ rc) & 15) * 8])

  // ---- prologue: stage chunks 0 and 1, full cfconv for chunk 0 ----
  STAGE(0, bid)
  if (1 < myChunks) STAGE(1, bid + PBLOCKS)
  __syncthreads();     // tables + pk[0]/pk[1] visible
  #pragma unroll
  for (int c = 0; c < 4; ++c) acc[c] = (f16x2)0;
  IG(A, 0, 0) IG(B, 0, 1)
  CG(A) IG(A, 0, 2)
  CG(B) IG(B, 0, 3)
  CG(A) IG(A, 0, 4)
  CG(B) IG(B, 0, 5)
  CG(A) IG(A, 0, 6)
  CG(B) IG(B, 0, 7)
  CG(A)
  CG(B)
  AGGW(0)
  __syncthreads();     // aggB[0] ready

  // ---- main loop: 3 barriers per chunk ----
  for (int s = 0; s < myChunks; ++s) {
    const int b  = s & 1;
    const int cc = bid + s * PBLOCKS;
    const bool hn = (s + 1 < myChunks);
    const int nb_ = b ^ 1;

    if (hn) {
      #pragma unroll
      for (int c = 0; c < 4; ++c) acc[c] = (f16x2)0;
    }

    // Phase 1: dense L1 on aggB[b] || cfconv groups 0-2 of next chunk
    if (hn) { IG(A, nb_, 0) IG(B, nb_, 1) }
    {
      const f16* aggp = &aggB[b][g * 2048];
      f32x4 dacc[2];
      #pragma unroll
      for (int t = 0; t < 2; ++t) dacc[t] = (f32x4){bb1[t], bb1[t], bb1[t], bb1[t]};
      #pragma unroll
      for (int k0i = 0; k0i < 4; ++k0i) {
        const f16x8 af = AFRAGP(aggp, k0i * 32);
        #pragma unroll
        for (int t = 0; t < 2; ++t)
          dacc[t] = __builtin_amdgcn_mfma_f32_16x16x32_f16(af, bw1[t][k0i], dacc[t], 0, 0, 0);
      }
      f16* hB = &sB[g * 2048];
      #pragma unroll
      for (int t = 0; t < 2; ++t) {
        const int c = wvg * 32 + t * 16 + rc;
        #pragma unroll
        for (int r = 0; r < 4; ++r) hB[swz(qk * 4 + r, c)] = (f16)ssp(dacc[t][r]);
      }
    }
    if (hn) { CG(A) IG(A, nb_, 2) CG(B) CG(A) }
    __syncthreads();   // B1: sB ready

    // Phase 2: dense L2 + residual || cfconv groups 3-5
    if (hn) { IG(A, nb_, 3) IG(B, nb_, 4) }
    {
      const f16* hB = &sB[g * 2048];
      f16* hX = &sX[g * 2048];
      f32x4 dacc[2];
      #pragma unroll
      for (int t = 0; t < 2; ++t) dacc[t] = (f32x4){bb2[t], bb2[t], bb2[t], bb2[t]};
      #pragma unroll
      for (int k0i = 0; k0i < 4; ++k0i) {
        const f16x8 af = AFRAGP(hB, k0i * 32);
        #pragma unroll
        for (int t = 0; t < 2; ++t)
          dacc[t] = __builtin_amdgcn_mfma_f32_16x16x32_f16(af, bw2[t][k0i], dacc[t], 0, 0, 0);
      }
      #pragma unroll
      for (int t = 0; t < 2; ++t) {
        const int c = wvg * 32 + t * 16 + rc;
        #pragma unroll
        for (int r = 0; r < 4; ++r) {
          const int mm = qk * 4 + r;
          const float x = embed[(size_t)sZb[b][g * 16 + mm] * 128 + c] + dacc[t][r];
          hX[swz(mm, c)] = (f16)x;
        }
      }
    }
    if (hn) { CG(A) IG(A, nb_, 5) CG(B) CG(A) }
    __syncthreads();   // B2: sX ready

    // Phase 3: MLP || cfconv groups 6-7 + agg write || stage chunk s+2
    if (hn) { IG(A, nb_, 6) IG(B, nb_, 7) }
    if (s + 2 < myChunks) STAGE(b, bid + (s + 2) * PBLOCKS)  // buffer b free since B3 of s-1
    {
      const f16* hX = &sX[g * 2048];
      f32x4 a2 = (f32x4){bm, bm, bm, bm};
      #pragma unroll
      for (int k0i = 0; k0i < 4; ++k0i)
        a2 = __builtin_amdgcn_mfma_f32_16x16x32_f16(AFRAGP(hX, k0i * 32), bwm[k0i], a2, 0, 0, 0);
      #pragma unroll
      for (int r = 0; r < 4; ++r) {
        const int atom = cc * 32 + g * 16 + qk * 4 + r;
        if (atom < N_ATOMS) vsum = fmaf(ssp(a2[r]), cm, vsum);
      }
    }
    if (hn) { CG(A) CG(B) AGGW(nb_) }
    __syncthreads();   // B3: aggB[nb_] + s_pk[b] complete; sB/sX free
  }
#undef STAGE
#undef IG
#undef CG
#undef AGGW
#undef AFRAGP

  // ---- block reduce -> one atomicAdd per block ----
  #pragma unroll
  for (int o = 1; o < 64; o <<= 1) vsum += __shfl_xor(vsum, o, 64);
  if (l == 0) sRed[w] = vsum;
  __syncthreads();
  if (tid == 0) {
    float sF = 0.0f;
    #pragma unroll
    for (int i = 0; i < 8; ++i) sF += sRed[i];
    atomicAdd(out, 20.0f * sF);
  }
}

extern "C" void kernel_launch(void* const* d_in, const int* in_sizes, int n_in,
                              void* d_out, int out_size, void* d_ws, size_t ws_size,
                              hipStream_t stream) {
  const float* dR    = (const float*)d_in[0];
  const int*   Z     = (const int*)  d_in[1];
  const int*   nbr   = (const int*)  d_in[2];
  const float* embed = (const float*)d_in[3];
  const float* fw1   = (const float*)d_in[4];
  const float* fb1   = (const float*)d_in[5];
  const float* fw2   = (const float*)d_in[6];
  const float* fb2   = (const float*)d_in[7];
  const float* in2f  = (const float*)d_in[8];
  const float* w1    = (const float*)d_in[9];
  const float* b1    = (const float*)d_in[10];
  const float* w2    = (const float*)d_in[11];
  const float* b2    = (const float*)d_in[12];
  const float* mw1   = (const float*)d_in[13];
  const float* mb1   = (const float*)d_in[14];
  const float* mw2   = (const float*)d_in[15];
  const float* mb2   = (const float*)d_in[16];
  float* out = (float*)d_out;

  char* ws = (char*)d_ws;
  f16*    tabh    = (f16*)ws;                               // 48 KB
  f16*    ytab    = (f16*)(ws + (size_t)64 * 1024);         // 25.6 KB
  f16*    w1ht    = (f16*)(ws + (size_t)128 * 1024);        // 32 KB
  f16*    w2ht    = (f16*)(ws + (size_t)192 * 1024);        // 32 KB
  f16*    mw1ht   = (f16*)(ws + (size_t)256 * 1024);        // 16 KB
  uint_t* pkAll   = (uint_t*)(ws + (size_t)1024 * 1024);    // 6.4 MB

  prep_all_kernel<<<NTB + 64 + PKB, 256, 0, stream>>>(fw1, fb1, fw2, fb2,
      w1, w2, mw1, embed, in2f, dR, nbr, Z, mb2,
      tabh, ytab, w1ht, w2ht, mw1ht, pkAll, out);
  fused_kernel<<<PBLOCKS, 512, 0, stream>>>(pkAll, Z, embed,
      tabh, ytab, w1ht, b1, w2ht, b2, mw1ht, mb1, mw2, out);
}